// Round 5
// baseline (2478.039 us; speedup 1.0000x reference)
//
#include <hip/hip_runtime.h>
#include <math.h>

#define LN 8      // layers
#define NRBF 256
#define FD 16
#define OUTD 3
#define KC (-0.72134752044f)   // -0.5 * log2(e)

typedef __attribute__((ext_vector_type(8))) short short8;    // 8 x bf16
typedef __attribute__((ext_vector_type(16))) float floatx16;
typedef __attribute__((ext_vector_type(2))) float floatx2;

__device__ __forceinline__ short f2bf(float f) {
    unsigned u = __builtin_bit_cast(unsigned, f);
    u += 0x7fffu + ((u >> 16) & 1u);          // RNE
    return (short)(u >> 16);
}

// 32x32x16 layouts, t-MAJOR (so one n-tile's full j-chain is contiguous):
//   PKB: short8 entry g = t*1024 + j*128 + s*64 + l   (16 KB per t)
//        lane l: n = t*32 + (l&31), kh = l>>5; elem e: f = s*8 + kh*4 + (e>>1)
//        e even -> KC*A_f ; e odd -> -2*KC*A_f*C_f    (A = exp(beta))
//   EPI: float4 entry (t*8+j)*32 + (n&31) = {W'0, W'1, W'2, 0}   (4 KB per t)
//        W'o = W[o][j*256+n] * exp2(KC * t3prefix_j[n])

__global__ __launch_bounds__(256) void prep(
    const float* __restrict__ centers, const float* __restrict__ betas,
    const float* __restrict__ W, short* __restrict__ PKB, float* __restrict__ EPI)
{
    __shared__ float ls[LN * 32];
    int blk = blockIdx.x;
    int tid = threadIdx.x;
    if (blk < 32) {
        int g  = blk * 256 + tid;          // = t*1024 + j*128 + s*64 + l (linear)
        int l  = g & 63;
        int s  = (g >> 6) & 1;
        int j  = (g >> 7) & 7;
        int t  = g >> 10;
        int n  = t * 32 + (l & 31);
        int kh = l >> 5;
        int f0 = s * 8 + kh * 4;
        size_t base = ((size_t)(j * NRBF + n)) * FD + f0;
        float4 bq = *(const float4*)(betas + base);
        float4 cq = *(const float4*)(centers + base);
        float a0 = KC * __expf(bq.x), a1 = KC * __expf(bq.y);
        float a2 = KC * __expf(bq.z), a3 = KC * __expf(bq.w);
        short8 v;
        v[0] = f2bf(a0); v[1] = f2bf(-2.0f * a0 * cq.x);
        v[2] = f2bf(a1); v[3] = f2bf(-2.0f * a1 * cq.y);
        v[4] = f2bf(a2); v[5] = f2bf(-2.0f * a2 * cq.z);
        v[6] = f2bf(a3); v[7] = f2bf(-2.0f * a3 * cq.w);
        *((short8*)(PKB + (size_t)g * 8)) = v;
    } else {
        int jj = tid >> 5;                  // 0..7
        int nl = tid & 31;
        int n  = (blk - 32) * 32 + nl;
        const float* bp = betas   + ((size_t)(jj * NRBF + n)) * FD;
        const float* cp = centers + ((size_t)(jj * NRBF + n)) * FD;
        float s = 0.f;
#pragma unroll
        for (int q = 0; q < 4; ++q) {
            float4 bq = *(const float4*)(bp + q * 4);
            float4 cq = *(const float4*)(cp + q * 4);
            s = fmaf(__expf(bq.x) * cq.x, cq.x, s);
            s = fmaf(__expf(bq.y) * cq.y, cq.y, s);
            s = fmaf(__expf(bq.z) * cq.z, cq.z, s);
            s = fmaf(__expf(bq.w) * cq.w, cq.w, s);
        }
        ls[jj * 32 + nl] = s;
        __syncthreads();
        float t3 = 0.f;
        for (int j2 = 0; j2 <= jj; ++j2) t3 += ls[j2 * 32 + nl];
        float E = __builtin_amdgcn_exp2f(KC * t3);
        float4 e;
        e.x = W[0 * (LN * NRBF) + jj * NRBF + n] * E;
        e.y = W[1 * (LN * NRBF) + jj * NRBF + n] * E;
        e.z = W[2 * (LN * NRBF) + jj * NRBF + n] * E;
        e.w = 0.f;
        ((float4*)EPI)[((n >> 5) * 8 + jj) * 32 + (n & 31)] = e;
    }
}

// build an A-fragment: elem e even -> x_f^2, odd -> x_f  (f = e>>1 of the quad)
// NOTE: macro parameter must NOT be named x/y/z/w (member-access capture!)
#define CVT(dst, vv)  do {                                         \
        short8 f_;                                                 \
        f_[0] = f2bf((vv).x * (vv).x); f_[1] = f2bf((vv).x);       \
        f_[2] = f2bf((vv).y * (vv).y); f_[3] = f2bf((vv).y);       \
        f_[4] = f2bf((vv).z * (vv).z); f_[5] = f2bf((vv).z);       \
        f_[6] = f2bf((vv).w * (vv).w); f_[7] = f2bf((vv).w);       \
        (dst) = f_; } while (0)

// One wave owns a 32-sample tile. t-OUTER / j-INNER: for each n-tile t
// (32 RBF centers), run the whole 8-layer prefix chain with a SINGLE
// floatx16 accumulator. Per (t,j): 2 MFMAs + 16 exps + projection.
// PKB/EPI per-t slices (16+4 KB) double-buffered in LDS (global_load_lds 16B).
// SPILL POST-MORTEM (rounds 2-4): full 8x8 unroll gave the scheduler one
// giant region; it hoisted ~96 regs of ds_read/ep prefetch past the 165-reg
// named state -> scratch churn (GBs of HBM). Fix: unroll 1 on t, unroll 2
// on j -> small scheduling window; waves (not ILP) hide latency.
__global__ __launch_bounds__(256) void rbf_mfma(
    const float* __restrict__ feats, const short* __restrict__ PKB,
    const float* __restrict__ EPI, const float* __restrict__ bias,
    float* __restrict__ out, int B)
{
    __shared__ short8 pk_s[2][16 * 64];   // 2 x 16 KB
    __shared__ float4 ep_s[2][8 * 32];    // 2 x 4 KB

    int tid  = threadIdx.x;
    int lane = tid & 63;
    int w    = tid >> 6;
    int ntile = (B + 31) >> 5;
    int tile = blockIdx.x * 4 + w;
    bool tvalid = (tile < ntile);
    if (!tvalid) tile = ntile - 1;        // duplicate work, no store
    int b0  = tile * 32;
    int s32 = lane & 31;                  // sample-in-tile for A, n-in-32 for D
    int kh  = lane >> 5;
    int brow = b0 + s32; if (brow >= B) brow = B - 1;
    const float* xrow = feats + (size_t)brow * (LN * FD) + kh * 4;

#define STAGE(buf, tv)                                                          \
    do {                                                                        \
        _Pragma("unroll")                                                       \
        for (int i = 0; i < 4; ++i) {                                           \
            const short* gp = PKB + ((size_t)(tv) * 1024 + (w * 4 + i) * 64 + lane) * 8; \
            __builtin_amdgcn_global_load_lds(                                   \
                (const __attribute__((address_space(1))) void*)gp,              \
                (__attribute__((address_space(3))) void*)&pk_s[buf][(w * 4 + i) * 64], \
                16, 0, 0);                                                      \
        }                                                                       \
        const float* ge = EPI + ((size_t)(tv) * 256 + w * 64 + lane) * 4;       \
        __builtin_amdgcn_global_load_lds(                                       \
            (const __attribute__((address_space(1))) void*)ge,                  \
            (__attribute__((address_space(3))) void*)&ep_s[buf][w * 64],        \
            16, 0, 0);                                                          \
    } while (0)

    STAGE(0, 0);   // issue first LDS fill; hides under the af-build below

    // A-fragments for all 8 layers (64 VGPRs), built once
    short8 af0[LN], af1[LN];
#pragma unroll
    for (int j = 0; j < LN; ++j) {
        float4 xa = *(const float4*)(xrow + j * FD);
        float4 xb = *(const float4*)(xrow + j * FD + 8);
        CVT(af0[j], xa);
        CVT(af1[j], xb);
    }

    floatx2 o01[16];
    float   o2[16];
#pragma unroll
    for (int r = 0; r < 16; ++r) { o01[r] = (floatx2){0.f, 0.f}; o2[r] = 0.f; }

    __syncthreads();

#pragma unroll 1
    for (int t = 0; t < 8; ++t) {
        int cur = t & 1;
        if (t < 7) STAGE(cur ^ 1, t + 1);

        floatx16 acc;
#pragma unroll
        for (int q = 0; q < 16; ++q) acc[q] = 0.f;

#pragma unroll 2
        for (int j = 0; j < LN; ++j) {
            short8 bf0 = pk_s[cur][(j * 2 + 0) * 64 + lane];
            short8 bf1 = pk_s[cur][(j * 2 + 1) * 64 + lane];
            acc = __builtin_amdgcn_mfma_f32_32x32x16_bf16(af0[j], bf0, acc, 0, 0, 0);
            acc = __builtin_amdgcn_mfma_f32_32x32x16_bf16(af1[j], bf1, acc, 0, 0, 0);

            float4 e = ep_s[cur][j * 32 + s32];
            floatx2 exy = {e.x, e.y};
#pragma unroll
            for (int r = 0; r < 16; ++r) {
                float rv = __builtin_amdgcn_exp2f(acc[r]);
                o01[r] += (floatx2){rv, rv} * exy;
                o2[r]   = fmaf(rv, e.z, o2[r]);
            }
        }
        __syncthreads();
    }
#undef STAGE

    // reduce over the 32 n-lanes (within each lane-half; rows differ by kh)
    float bv = (s32 < OUTD) ? bias[s32] : 0.f;
#pragma unroll
    for (int r = 0; r < 16; ++r) {
        float ax = o01[r].x, ay = o01[r].y, az = o2[r];
        ax += __shfl_xor(ax, 1);  ay += __shfl_xor(ay, 1);  az += __shfl_xor(az, 1);
        ax += __shfl_xor(ax, 2);  ay += __shfl_xor(ay, 2);  az += __shfl_xor(az, 2);
        ax += __shfl_xor(ax, 4);  ay += __shfl_xor(ay, 4);  az += __shfl_xor(az, 4);
        ax += __shfl_xor(ax, 8);  ay += __shfl_xor(ay, 8);  az += __shfl_xor(az, 8);
        ax += __shfl_xor(ax, 16); ay += __shfl_xor(ay, 16); az += __shfl_xor(az, 16);
        if (tvalid && s32 < OUTD) {
            int row = (r & 3) + 8 * (r >> 2) + 4 * kh;   // D-row = sample-in-tile
            int gr  = b0 + row;
            float val = (s32 == 0) ? ax : (s32 == 1) ? ay : az;
            if (gr < B) out[(size_t)gr * OUTD + s32] = val + bv;
        }
    }
}

extern "C" void kernel_launch(void* const* d_in, const int* in_sizes, int n_in,
                              void* d_out, int out_size, void* d_ws, size_t ws_size,
                              hipStream_t stream) {
    // inputs: 0=x (UNUSED by reference), 1=feats, 2=centers, 3=betas, 4=W, 5=b
    const float* feats   = (const float*)d_in[1];
    const float* centers = (const float*)d_in[2];
    const float* betas   = (const float*)d_in[3];
    const float* W       = (const float*)d_in[4];
    const float* bias    = (const float*)d_in[5];
    float* out = (float*)d_out;
    int B = in_sizes[1] / (LN * FD);

    short* PKB = (short*)d_ws;                       // 65536 shorts = 128 KB
    float* EPI = (float*)((char*)d_ws + 65536 * 2);  // 8192 floats = 32 KB

    prep<<<40, 256, 0, stream>>>(centers, betas, W, PKB, EPI);

    int tiles  = (B + 31) / 32;
    int blocks = (tiles + 3) / 4;
    rbf_mfma<<<blocks, 256, 0, stream>>>(feats, PKB, EPI, bias, out, B);
}

// Round 6
// 176.327 us; speedup vs baseline: 14.0537x; 14.0537x over previous
//
#include <hip/hip_runtime.h>
#include <math.h>

#define LN 8      // layers
#define NRBF 256
#define FD 16
#define OUTD 3
#define KC (-0.72134752044f)   // -0.5 * log2(e)

typedef __attribute__((ext_vector_type(8))) short short8;    // 8 x bf16
typedef __attribute__((ext_vector_type(16))) float floatx16;
typedef __attribute__((ext_vector_type(2))) float floatx2;

__device__ __forceinline__ short f2bf(float f) {
    unsigned u = __builtin_bit_cast(unsigned, f);
    u += 0x7fffu + ((u >> 16) & 1u);          // RNE
    return (short)(u >> 16);
}

// 32x32x16 layouts, t-MAJOR (so one n-tile's full j-chain is contiguous):
//   PKB: short8 entry g = t*1024 + j*128 + s*64 + l   (16 KB per t)
//        lane l: n = t*32 + (l&31), kh = l>>5; elem e: f = s*8 + kh*4 + (e>>1)
//        e even -> KC*A_f ; e odd -> -2*KC*A_f*C_f    (A = exp(beta))
//   EPI: float4 entry (t*8+j)*32 + (n&31) = {W'0, W'1, W'2, 0}   (4 KB per t)
//        W'o = W[o][j*256+n] * exp2(KC * t3prefix_j[n])

__global__ __launch_bounds__(256) void prep(
    const float* __restrict__ centers, const float* __restrict__ betas,
    const float* __restrict__ W, short* __restrict__ PKB, float* __restrict__ EPI)
{
    __shared__ float ls[LN * 32];
    int blk = blockIdx.x;
    int tid = threadIdx.x;
    if (blk < 32) {
        int g  = blk * 256 + tid;          // = t*1024 + j*128 + s*64 + l (linear)
        int l  = g & 63;
        int s  = (g >> 6) & 1;
        int j  = (g >> 7) & 7;
        int t  = g >> 10;
        int n  = t * 32 + (l & 31);
        int kh = l >> 5;
        int f0 = s * 8 + kh * 4;
        size_t base = ((size_t)(j * NRBF + n)) * FD + f0;
        float4 bq = *(const float4*)(betas + base);
        float4 cq = *(const float4*)(centers + base);
        float a0 = KC * __expf(bq.x), a1 = KC * __expf(bq.y);
        float a2 = KC * __expf(bq.z), a3 = KC * __expf(bq.w);
        short8 v;
        v[0] = f2bf(a0); v[1] = f2bf(-2.0f * a0 * cq.x);
        v[2] = f2bf(a1); v[3] = f2bf(-2.0f * a1 * cq.y);
        v[4] = f2bf(a2); v[5] = f2bf(-2.0f * a2 * cq.z);
        v[6] = f2bf(a3); v[7] = f2bf(-2.0f * a3 * cq.w);
        *((short8*)(PKB + (size_t)g * 8)) = v;
    } else {
        int jj = tid >> 5;                  // 0..7
        int nl = tid & 31;
        int n  = (blk - 32) * 32 + nl;
        const float* bp = betas   + ((size_t)(jj * NRBF + n)) * FD;
        const float* cp = centers + ((size_t)(jj * NRBF + n)) * FD;
        float s = 0.f;
#pragma unroll
        for (int q = 0; q < 4; ++q) {
            float4 bq = *(const float4*)(bp + q * 4);
            float4 cq = *(const float4*)(cp + q * 4);
            s = fmaf(__expf(bq.x) * cq.x, cq.x, s);
            s = fmaf(__expf(bq.y) * cq.y, cq.y, s);
            s = fmaf(__expf(bq.z) * cq.z, cq.z, s);
            s = fmaf(__expf(bq.w) * cq.w, cq.w, s);
        }
        ls[jj * 32 + nl] = s;
        __syncthreads();
        float t3 = 0.f;
        for (int j2 = 0; j2 <= jj; ++j2) t3 += ls[j2 * 32 + nl];
        float E = __builtin_amdgcn_exp2f(KC * t3);
        float4 e;
        e.x = W[0 * (LN * NRBF) + jj * NRBF + n] * E;
        e.y = W[1 * (LN * NRBF) + jj * NRBF + n] * E;
        e.z = W[2 * (LN * NRBF) + jj * NRBF + n] * E;
        e.w = 0.f;
        ((float4*)EPI)[((n >> 5) * 8 + jj) * 32 + (n & 31)] = e;
    }
}

// build an A-fragment: elem e even -> x_f^2, odd -> x_f  (f = e>>1 of the quad)
// NOTE: macro parameter must NOT be named x/y/z/w (member-access capture!)
#define CVT(dst, vv)  do {                                         \
        short8 f_;                                                 \
        f_[0] = f2bf((vv).x * (vv).x); f_[1] = f2bf((vv).x);       \
        f_[2] = f2bf((vv).y * (vv).y); f_[3] = f2bf((vv).y);       \
        f_[4] = f2bf((vv).z * (vv).z); f_[5] = f2bf((vv).z);       \
        f_[6] = f2bf((vv).w * (vv).w); f_[7] = f2bf((vv).w);       \
        (dst) = f_; } while (0)

// One wave owns a 32-sample tile. t-OUTER / j-INNER: for each n-tile t
// (32 RBF centers), run the whole 8-layer prefix chain with a SINGLE
// floatx16 accumulator. Per (t,j): 2 MFMAs + 16 exps + projection.
// PKB/EPI per-t slices (16+4 KB) double-buffered in LDS (global_load_lds 16B).
//
// REGISTER DISCIPLINE (rounds 2-5 post-mortems):
//  - t-loop MUST be unroll 1: full t*j unroll let the scheduler hoist ~96
//    regs of prefetch -> scratch spill churn (GBs of HBM traffic, R3/R4).
//  - j-loop MUST be fully unrolled: runtime j made af0[j]/af1[j]
//    dynamically-indexed register arrays -> select-chain lowering, 30x
//    VALU amplification (R5, VALUBusy 40% at 2455 us).
//  - launch_bounds must NOT request min-waves: (256,2) split the unified
//    file 128 arch + 128 acc and spilled (R2/R3).
__global__ __launch_bounds__(256) void rbf_mfma(
    const float* __restrict__ feats, const short* __restrict__ PKB,
    const float* __restrict__ EPI, const float* __restrict__ bias,
    float* __restrict__ out, int B)
{
    __shared__ short8 pk_s[2][16 * 64];   // 2 x 16 KB
    __shared__ float4 ep_s[2][8 * 32];    // 2 x 4 KB

    int tid  = threadIdx.x;
    int lane = tid & 63;
    int w    = tid >> 6;
    int ntile = (B + 31) >> 5;
    int tile = blockIdx.x * 4 + w;
    bool tvalid = (tile < ntile);
    if (!tvalid) tile = ntile - 1;        // duplicate work, no store
    int b0  = tile * 32;
    int s32 = lane & 31;                  // sample-in-tile for A, n-in-32 for D
    int kh  = lane >> 5;
    int brow = b0 + s32; if (brow >= B) brow = B - 1;
    const float* xrow = feats + (size_t)brow * (LN * FD) + kh * 4;

#define STAGE(buf, tv)                                                          \
    do {                                                                        \
        _Pragma("unroll")                                                       \
        for (int i = 0; i < 4; ++i) {                                           \
            const short* gp = PKB + ((size_t)(tv) * 1024 + (w * 4 + i) * 64 + lane) * 8; \
            __builtin_amdgcn_global_load_lds(                                   \
                (const __attribute__((address_space(1))) void*)gp,              \
                (__attribute__((address_space(3))) void*)&pk_s[buf][(w * 4 + i) * 64], \
                16, 0, 0);                                                      \
        }                                                                       \
        const float* ge = EPI + ((size_t)(tv) * 256 + w * 64 + lane) * 4;       \
        __builtin_amdgcn_global_load_lds(                                       \
            (const __attribute__((address_space(1))) void*)ge,                  \
            (__attribute__((address_space(3))) void*)&ep_s[buf][w * 64],        \
            16, 0, 0);                                                          \
    } while (0)

    STAGE(0, 0);   // issue first LDS fill; hides under the af-build below

    // A-fragments for all 8 layers (64 VGPRs), built once, STATIC index only
    short8 af0[LN], af1[LN];
#pragma unroll
    for (int j = 0; j < LN; ++j) {
        float4 xa = *(const float4*)(xrow + j * FD);
        float4 xb = *(const float4*)(xrow + j * FD + 8);
        CVT(af0[j], xa);
        CVT(af1[j], xb);
    }

    floatx2 o01[16];
    float   o2[16];
#pragma unroll
    for (int r = 0; r < 16; ++r) { o01[r] = (floatx2){0.f, 0.f}; o2[r] = 0.f; }

    __syncthreads();

#pragma unroll 1
    for (int t = 0; t < 8; ++t) {
        int cur = t & 1;
        if (t < 7) STAGE(cur ^ 1, t + 1);

        floatx16 acc;
#pragma unroll
        for (int q = 0; q < 16; ++q) acc[q] = 0.f;

#pragma unroll
        for (int j = 0; j < LN; ++j) {
            short8 bf0 = pk_s[cur][(j * 2 + 0) * 64 + lane];
            short8 bf1 = pk_s[cur][(j * 2 + 1) * 64 + lane];
            acc = __builtin_amdgcn_mfma_f32_32x32x16_bf16(af0[j], bf0, acc, 0, 0, 0);
            acc = __builtin_amdgcn_mfma_f32_32x32x16_bf16(af1[j], bf1, acc, 0, 0, 0);

            float4 e = ep_s[cur][j * 32 + s32];
            floatx2 exy = {e.x, e.y};
#pragma unroll
            for (int r = 0; r < 16; ++r) {
                float rv = __builtin_amdgcn_exp2f(acc[r]);
                o01[r] += (floatx2){rv, rv} * exy;
                o2[r]   = fmaf(rv, e.z, o2[r]);
            }
        }
        __syncthreads();
    }
#undef STAGE

    // reduce over the 32 n-lanes (within each lane-half; rows differ by kh)
    float bv = (s32 < OUTD) ? bias[s32] : 0.f;
#pragma unroll
    for (int r = 0; r < 16; ++r) {
        float ax = o01[r].x, ay = o01[r].y, az = o2[r];
        ax += __shfl_xor(ax, 1);  ay += __shfl_xor(ay, 1);  az += __shfl_xor(az, 1);
        ax += __shfl_xor(ax, 2);  ay += __shfl_xor(ay, 2);  az += __shfl_xor(az, 2);
        ax += __shfl_xor(ax, 4);  ay += __shfl_xor(ay, 4);  az += __shfl_xor(az, 4);
        ax += __shfl_xor(ax, 8);  ay += __shfl_xor(ay, 8);  az += __shfl_xor(az, 8);
        ax += __shfl_xor(ax, 16); ay += __shfl_xor(ay, 16); az += __shfl_xor(az, 16);
        if (tvalid && s32 < OUTD) {
            int row = (r & 3) + 8 * (r >> 2) + 4 * kh;   // D-row = sample-in-tile
            int gr  = b0 + row;
            float val = (s32 == 0) ? ax : (s32 == 1) ? ay : az;
            if (gr < B) out[(size_t)gr * OUTD + s32] = val + bv;
        }
    }
}

extern "C" void kernel_launch(void* const* d_in, const int* in_sizes, int n_in,
                              void* d_out, int out_size, void* d_ws, size_t ws_size,
                              hipStream_t stream) {
    // inputs: 0=x (UNUSED by reference), 1=feats, 2=centers, 3=betas, 4=W, 5=b
    const float* feats   = (const float*)d_in[1];
    const float* centers = (const float*)d_in[2];
    const float* betas   = (const float*)d_in[3];
    const float* W       = (const float*)d_in[4];
    const float* bias    = (const float*)d_in[5];
    float* out = (float*)d_out;
    int B = in_sizes[1] / (LN * FD);

    short* PKB = (short*)d_ws;                       // 65536 shorts = 128 KB
    float* EPI = (float*)((char*)d_ws + 65536 * 2);  // 8192 floats = 32 KB

    prep<<<40, 256, 0, stream>>>(centers, betas, W, PKB, EPI);

    int tiles  = (B + 31) / 32;
    int blocks = (tiles + 3) / 4;
    rbf_mfma<<<blocks, 256, 0, stream>>>(feats, PKB, EPI, bias, out, B);
}

// Round 7
// 173.684 us; speedup vs baseline: 14.2675x; 1.0152x over previous
//
#include <hip/hip_runtime.h>
#include <math.h>

#define LN 8      // layers
#define NRBF 256
#define FD 16
#define OUTD 3
#define KC (-0.72134752044f)   // -0.5 * log2(e)

typedef __attribute__((ext_vector_type(8))) short short8;    // 8 x bf16
typedef __attribute__((ext_vector_type(16))) float floatx16;
typedef __attribute__((ext_vector_type(2))) float floatx2;

__device__ __forceinline__ short f2bf(float f) {
    unsigned u = __builtin_bit_cast(unsigned, f);
    u += 0x7fffu + ((u >> 16) & 1u);          // RNE
    return (short)(u >> 16);
}

// 32x32x16 layouts, t-MAJOR (so one n-tile's full j-chain is contiguous):
//   PKB: short8 entry g = t*1024 + j*128 + s*64 + l   (16 KB per t)
//        lane l: n = t*32 + (l&31), kh = l>>5; elem e: f = s*8 + kh*4 + (e>>1)
//        e even -> KC*A_f ; e odd -> -2*KC*A_f*C_f    (A = exp(beta))
//   EPI: float4 entry (t*8+j)*32 + (n&31) = {W'0, W'1, W'2, 0}   (4 KB per t)
//        W'o = W[o][j*256+n] * exp2(KC * t3prefix_j[n])

__global__ __launch_bounds__(256) void prep(
    const float* __restrict__ centers, const float* __restrict__ betas,
    const float* __restrict__ W, short* __restrict__ PKB, float* __restrict__ EPI)
{
    __shared__ float ls[LN * 32];
    int blk = blockIdx.x;
    int tid = threadIdx.x;
    if (blk < 32) {
        int g  = blk * 256 + tid;          // = t*1024 + j*128 + s*64 + l (linear)
        int l  = g & 63;
        int s  = (g >> 6) & 1;
        int j  = (g >> 7) & 7;
        int t  = g >> 10;
        int n  = t * 32 + (l & 31);
        int kh = l >> 5;
        int f0 = s * 8 + kh * 4;
        size_t base = ((size_t)(j * NRBF + n)) * FD + f0;
        float4 bq = *(const float4*)(betas + base);
        float4 cq = *(const float4*)(centers + base);
        float a0 = KC * __expf(bq.x), a1 = KC * __expf(bq.y);
        float a2 = KC * __expf(bq.z), a3 = KC * __expf(bq.w);
        short8 v;
        v[0] = f2bf(a0); v[1] = f2bf(-2.0f * a0 * cq.x);
        v[2] = f2bf(a1); v[3] = f2bf(-2.0f * a1 * cq.y);
        v[4] = f2bf(a2); v[5] = f2bf(-2.0f * a2 * cq.z);
        v[6] = f2bf(a3); v[7] = f2bf(-2.0f * a3 * cq.w);
        *((short8*)(PKB + (size_t)g * 8)) = v;
    } else {
        int jj = tid >> 5;                  // 0..7
        int nl = tid & 31;
        int n  = (blk - 32) * 32 + nl;
        const float* bp = betas   + ((size_t)(jj * NRBF + n)) * FD;
        const float* cp = centers + ((size_t)(jj * NRBF + n)) * FD;
        float s = 0.f;
#pragma unroll
        for (int q = 0; q < 4; ++q) {
            float4 bq = *(const float4*)(bp + q * 4);
            float4 cq = *(const float4*)(cp + q * 4);
            s = fmaf(__expf(bq.x) * cq.x, cq.x, s);
            s = fmaf(__expf(bq.y) * cq.y, cq.y, s);
            s = fmaf(__expf(bq.z) * cq.z, cq.z, s);
            s = fmaf(__expf(bq.w) * cq.w, cq.w, s);
        }
        ls[jj * 32 + nl] = s;
        __syncthreads();
        float t3 = 0.f;
        for (int j2 = 0; j2 <= jj; ++j2) t3 += ls[j2 * 32 + nl];
        float E = __builtin_amdgcn_exp2f(KC * t3);
        float4 e;
        e.x = W[0 * (LN * NRBF) + jj * NRBF + n] * E;
        e.y = W[1 * (LN * NRBF) + jj * NRBF + n] * E;
        e.z = W[2 * (LN * NRBF) + jj * NRBF + n] * E;
        e.w = 0.f;
        ((float4*)EPI)[((n >> 5) * 8 + jj) * 32 + (n & 31)] = e;
    }
}

// build an A-fragment: elem e even -> x_f^2, odd -> x_f  (f = e>>1 of the quad)
// NOTE: macro parameter must NOT be named x/y/z/w (member-access capture!)
#define CVT(dst, vv)  do {                                         \
        short8 f_;                                                 \
        f_[0] = f2bf((vv).x * (vv).x); f_[1] = f2bf((vv).x);       \
        f_[2] = f2bf((vv).y * (vv).y); f_[3] = f2bf((vv).y);       \
        f_[4] = f2bf((vv).z * (vv).z); f_[5] = f2bf((vv).z);       \
        f_[6] = f2bf((vv).w * (vv).w); f_[7] = f2bf((vv).w);       \
        (dst) = f_; } while (0)

// One wave owns a 32-sample tile. t-OUTER / j-INNER, with a ONE-J-LAG
// software pipeline: per j, the MFMA pair updates acc (layer-j prefix),
// while the exps/projection for layer j-1 run on accp (snapshot of acc
// after layer j-1). This breaks the acc anti-dependency that serialized
// MFMA-latency -> 224cyc of exps -> next MFMA (R6: 120us at 26% VALUBusy).
// The snapshot costs 16 v_mov + 16 VGPRs.
//
// REGISTER DISCIPLINE (rounds 2-6 post-mortems):
//  - t-loop MUST be unroll 1: full t*j unroll let the scheduler hoist ~96
//    regs of prefetch -> scratch spill churn (GBs of HBM traffic, R3/R4).
//  - j-loop MUST be fully unrolled: runtime j made af0[j]/af1[j]
//    dynamically-indexed register arrays -> select-chain lowering, 30x
//    VALU amplification (R5, VALUBusy 40% at 2455 us).
//  - launch_bounds must NOT request min-waves: (256,2) split the unified
//    file 128 arch + 128 acc and spilled (R2/R3).
//  - spill sentinel: FETCH ~26MB / WRITE ~1.2MB. GB-scale => scratch churn.
__global__ __launch_bounds__(256) void rbf_mfma(
    const float* __restrict__ feats, const short* __restrict__ PKB,
    const float* __restrict__ EPI, const float* __restrict__ bias,
    float* __restrict__ out, int B)
{
    __shared__ short8 pk_s[2][16 * 64];   // 2 x 16 KB
    __shared__ float4 ep_s[2][8 * 32];    // 2 x 4 KB

    int tid  = threadIdx.x;
    int lane = tid & 63;
    int w    = tid >> 6;
    int ntile = (B + 31) >> 5;
    int tile = blockIdx.x * 4 + w;
    bool tvalid = (tile < ntile);
    if (!tvalid) tile = ntile - 1;        // duplicate work, no store
    int b0  = tile * 32;
    int s32 = lane & 31;                  // sample-in-tile for A, n-in-32 for D
    int kh  = lane >> 5;
    int brow = b0 + s32; if (brow >= B) brow = B - 1;
    const float* xrow = feats + (size_t)brow * (LN * FD) + kh * 4;

#define STAGE(buf, tv)                                                          \
    do {                                                                        \
        _Pragma("unroll")                                                       \
        for (int i = 0; i < 4; ++i) {                                           \
            const short* gp = PKB + ((size_t)(tv) * 1024 + (w * 4 + i) * 64 + lane) * 8; \
            __builtin_amdgcn_global_load_lds(                                   \
                (const __attribute__((address_space(1))) void*)gp,              \
                (__attribute__((address_space(3))) void*)&pk_s[buf][(w * 4 + i) * 64], \
                16, 0, 0);                                                      \
        }                                                                       \
        const float* ge = EPI + ((size_t)(tv) * 256 + w * 64 + lane) * 4;       \
        __builtin_amdgcn_global_load_lds(                                       \
            (const __attribute__((address_space(1))) void*)ge,                  \
            (__attribute__((address_space(3))) void*)&ep_s[buf][w * 64],        \
            16, 0, 0);                                                          \
    } while (0)

// exps + projection for one layer's prefix (reads ACC snapshot + ep float4)
#define EXPPROJ(accv, ev)                                          \
    do {                                                           \
        floatx2 exy_ = { (ev).x, (ev).y };                         \
        _Pragma("unroll")                                          \
        for (int r_ = 0; r_ < 16; ++r_) {                          \
            float rv_ = __builtin_amdgcn_exp2f((accv)[r_]);        \
            o01[r_] += (floatx2){rv_, rv_} * exy_;                 \
            o2[r_]   = fmaf(rv_, (ev).z, o2[r_]);                  \
        }                                                          \
    } while (0)

    STAGE(0, 0);   // issue first LDS fill; hides under the af-build below

    // A-fragments for all 8 layers (64 VGPRs), built once, STATIC index only
    short8 af0[LN], af1[LN];
#pragma unroll
    for (int j = 0; j < LN; ++j) {
        float4 xa = *(const float4*)(xrow + j * FD);
        float4 xb = *(const float4*)(xrow + j * FD + 8);
        CVT(af0[j], xa);
        CVT(af1[j], xb);
    }

    floatx2 o01[16];
    float   o2[16];
#pragma unroll
    for (int r = 0; r < 16; ++r) { o01[r] = (floatx2){0.f, 0.f}; o2[r] = 0.f; }

    __syncthreads();

#pragma unroll 1
    for (int t = 0; t < 8; ++t) {
        int cur = t & 1;
        if (t < 7) STAGE(cur ^ 1, t + 1);

        floatx16 acc;
#pragma unroll
        for (int q = 0; q < 16; ++q) acc[q] = 0.f;
        floatx16 accp;   // one-j-lag snapshot (written before first read)

#pragma unroll
        for (int j = 0; j < LN; ++j) {
            short8 bf0 = pk_s[cur][(j * 2 + 0) * 64 + lane];
            short8 bf1 = pk_s[cur][(j * 2 + 1) * 64 + lane];
            acc = __builtin_amdgcn_mfma_f32_32x32x16_bf16(af0[j], bf0, acc, 0, 0, 0);
            acc = __builtin_amdgcn_mfma_f32_32x32x16_bf16(af1[j], bf1, acc, 0, 0, 0);

            if (j > 0) {                   // finish layer j-1 while MFMA j flies
                float4 e = ep_s[cur][(j - 1) * 32 + s32];
                EXPPROJ(accp, e);
            }
            accp = acc;                    // snapshot after MFMA j completes
        }
        {   // tail: layer 7
            float4 e = ep_s[cur][7 * 32 + s32];
            EXPPROJ(accp, e);
        }
        __syncthreads();
    }
#undef STAGE
#undef EXPPROJ

    // reduce over the 32 n-lanes (within each lane-half; rows differ by kh)
    float bv = (s32 < OUTD) ? bias[s32] : 0.f;
#pragma unroll
    for (int r = 0; r < 16; ++r) {
        float ax = o01[r].x, ay = o01[r].y, az = o2[r];
        ax += __shfl_xor(ax, 1);  ay += __shfl_xor(ay, 1);  az += __shfl_xor(az, 1);
        ax += __shfl_xor(ax, 2);  ay += __shfl_xor(ay, 2);  az += __shfl_xor(az, 2);
        ax += __shfl_xor(ax, 4);  ay += __shfl_xor(ay, 4);  az += __shfl_xor(az, 4);
        ax += __shfl_xor(ax, 8);  ay += __shfl_xor(ay, 8);  az += __shfl_xor(az, 8);
        ax += __shfl_xor(ax, 16); ay += __shfl_xor(ay, 16); az += __shfl_xor(az, 16);
        if (tvalid && s32 < OUTD) {
            int row = (r & 3) + 8 * (r >> 2) + 4 * kh;   // D-row = sample-in-tile
            int gr  = b0 + row;
            float val = (s32 == 0) ? ax : (s32 == 1) ? ay : az;
            if (gr < B) out[(size_t)gr * OUTD + s32] = val + bv;
        }
    }
}

extern "C" void kernel_launch(void* const* d_in, const int* in_sizes, int n_in,
                              void* d_out, int out_size, void* d_ws, size_t ws_size,
                              hipStream_t stream) {
    // inputs: 0=x (UNUSED by reference), 1=feats, 2=centers, 3=betas, 4=W, 5=b
    const float* feats   = (const float*)d_in[1];
    const float* centers = (const float*)d_in[2];
    const float* betas   = (const float*)d_in[3];
    const float* W       = (const float*)d_in[4];
    const float* bias    = (const float*)d_in[5];
    float* out = (float*)d_out;
    int B = in_sizes[1] / (LN * FD);

    short* PKB = (short*)d_ws;                       // 65536 shorts = 128 KB
    float* EPI = (float*)((char*)d_ws + 65536 * 2);  // 8192 floats = 32 KB

    prep<<<40, 256, 0, stream>>>(centers, betas, W, PKB, EPI);

    int tiles  = (B + 31) / 32;
    int blocks = (tiles + 3) / 4;
    rbf_mfma<<<blocks, 256, 0, stream>>>(feats, PKB, EPI, bias, out, B);
}

// Round 8
// 139.637 us; speedup vs baseline: 17.7463x; 1.2438x over previous
//
#include <hip/hip_runtime.h>
#include <math.h>

#define LN 8      // layers
#define NRBF 256
#define FD 16
#define OUTD 3
#define KC (-0.72134752044f)   // -0.5 * log2(e)

typedef __attribute__((ext_vector_type(8))) short short8;    // 8 x bf16
typedef __attribute__((ext_vector_type(4))) float floatx4;
typedef __attribute__((ext_vector_type(2))) float floatx2;

__device__ __forceinline__ short f2bf(float f) {
    unsigned u = __builtin_bit_cast(unsigned, f);
    u += 0x7fffu + ((u >> 16) & 1u);          // RNE
    return (short)(u >> 16);
}

// 16x16x32 layouts, nt-MAJOR (one n-tile's full j-chain contiguous):
//   PKB: short8 entry g = nt*512 + j*64 + lane   (8 KB per nt, 128 KB total)
//        lane l: n = nt*16+(l&15), kq = l>>4; elem e: k = kq*8+e,
//        feature f = kq*4+(e>>1); e even -> KC*A_f ; e odd -> -2*KC*A_f*C_f
//   EPI: float4 entry nt*128 + j*16 + (n&15) = {W'0, W'1, W'2, 0}  (2 KB per nt)
//        W'o = W[o][j*256+n] * exp2(KC * t3prefix_j[n])

__global__ __launch_bounds__(256) void prep(
    const float* __restrict__ centers, const float* __restrict__ betas,
    const float* __restrict__ W, short* __restrict__ PKB, float* __restrict__ EPI)
{
    __shared__ float ls[LN * 32];
    int blk = blockIdx.x;
    int tid = threadIdx.x;
    if (blk < 32) {
        int g    = blk * 256 + tid;        // = nt*512 + j*64 + lane (linear)
        int lane = g & 63;
        int j    = (g >> 6) & 7;
        int nt   = g >> 9;
        int n    = nt * 16 + (lane & 15);
        int kq   = lane >> 4;
        size_t base = ((size_t)(j * NRBF + n)) * FD + kq * 4;
        float4 bq = *(const float4*)(betas + base);
        float4 cq = *(const float4*)(centers + base);
        float a0 = KC * __expf(bq.x), a1 = KC * __expf(bq.y);
        float a2 = KC * __expf(bq.z), a3 = KC * __expf(bq.w);
        short8 v;
        v[0] = f2bf(a0); v[1] = f2bf(-2.0f * a0 * cq.x);
        v[2] = f2bf(a1); v[3] = f2bf(-2.0f * a1 * cq.y);
        v[4] = f2bf(a2); v[5] = f2bf(-2.0f * a2 * cq.z);
        v[6] = f2bf(a3); v[7] = f2bf(-2.0f * a3 * cq.w);
        *((short8*)(PKB + (size_t)g * 8)) = v;
    } else {
        int jj = tid >> 5;                  // 0..7
        int nl = tid & 31;
        int n  = (blk - 32) * 32 + nl;
        const float* bp = betas   + ((size_t)(jj * NRBF + n)) * FD;
        const float* cp = centers + ((size_t)(jj * NRBF + n)) * FD;
        float s = 0.f;
#pragma unroll
        for (int q = 0; q < 4; ++q) {
            float4 bq = *(const float4*)(bp + q * 4);
            float4 cq = *(const float4*)(cp + q * 4);
            s = fmaf(__expf(bq.x) * cq.x, cq.x, s);
            s = fmaf(__expf(bq.y) * cq.y, cq.y, s);
            s = fmaf(__expf(bq.z) * cq.z, cq.z, s);
            s = fmaf(__expf(bq.w) * cq.w, cq.w, s);
        }
        ls[jj * 32 + nl] = s;
        __syncthreads();
        float t3 = 0.f;
        for (int j2 = 0; j2 <= jj; ++j2) t3 += ls[j2 * 32 + nl];
        float E = __builtin_amdgcn_exp2f(KC * t3);
        float4 e;
        e.x = W[0 * (LN * NRBF) + jj * NRBF + n] * E;
        e.y = W[1 * (LN * NRBF) + jj * NRBF + n] * E;
        e.z = W[2 * (LN * NRBF) + jj * NRBF + n] * E;
        e.w = 0.f;
        ((float4*)EPI)[((size_t)(n >> 4) * 128) + jj * 16 + (n & 15)] = e;
    }
}

// build an A-fragment: elem e even -> x_f^2, odd -> x_f  (f = kq*4 + e>>1)
// NOTE: macro parameter must NOT be named x/y/z/w (member-access capture!)
#define CVT(dst, vv)  do {                                         \
        short8 f_;                                                 \
        f_[0] = f2bf((vv).x * (vv).x); f_[1] = f2bf((vv).x);       \
        f_[2] = f2bf((vv).y * (vv).y); f_[3] = f2bf((vv).y);       \
        f_[4] = f2bf((vv).z * (vv).z); f_[5] = f2bf((vv).z);       \
        f_[6] = f2bf((vv).w * (vv).w); f_[7] = f2bf((vv).w);       \
        (dst) = f_; } while (0)

// One wave owns a 16-sample tile x all 256 n x 8 layers. nt-OUTER / j-INNER
// with one-j-lag pipeline: MFMA j updates acc while exps of layer j-1 run on
// accp. 16x16x32 (not 32x32x16) to keep per-wave state ~90 VGPR -> 5-6
// waves/SIMD. Rationale (R0/R6/R7): total VALU work is fixed ~75K cyc/SIMD
// (exp-dominated); duration = floor / VALUBusy-fill, and fill tracks resident
// waves (R0: 6 w/SIMD -> 51%; R7: 3 w/SIMD -> 32%). Occupancy IS the lever.
//
// REGISTER DISCIPLINE (rounds 2-7 post-mortems):
//  - nt-loop MUST be unroll 1 (scheduler hoist -> spill churn, R3/R4).
//  - j-loop MUST be fully unrolled (runtime j -> dyn-indexed reg arrays, R5).
//  - launch_bounds must NOT request min-waves (arch/acc split spill, R2/R3).
//  - spill sentinel: FETCH ~26MB / WRITE ~1.2MB. GB-scale => scratch churn.
__global__ __launch_bounds__(256) void rbf_mfma(
    const float* __restrict__ feats, const short* __restrict__ PKB,
    const float* __restrict__ EPI, const float* __restrict__ bias,
    float* __restrict__ out, int B)
{
    __shared__ short8 pk_s[2][8 * 64];    // 2 x 8 KB
    __shared__ float4 ep_s[2][8 * 16];    // 2 x 2 KB

    int tid  = threadIdx.x;
    int lane = tid & 63;
    int w    = tid >> 6;
    int ntile = (B + 15) >> 4;
    int tile = blockIdx.x * 4 + w;
    bool tvalid = (tile < ntile);
    if (!tvalid) tile = ntile - 1;        // duplicate work, no store
    int b0 = tile * 16;
    int m  = lane & 15;                   // sample-in-tile (A-row), D-col = n16
    int kq = lane >> 4;
    int brow = b0 + m; if (brow >= B) brow = B - 1;
    const float* xrow = feats + (size_t)brow * (LN * FD) + kq * 4;

#define STAGE(buf, ntv)                                                         \
    do {                                                                        \
        _Pragma("unroll")                                                       \
        for (int q = 0; q < 2; ++q) {                                           \
            const short* gp = PKB + ((size_t)(ntv) * 512 + w * 128 + q * 64 + lane) * 8; \
            __builtin_amdgcn_global_load_lds(                                   \
                (const __attribute__((address_space(1))) void*)gp,              \
                (__attribute__((address_space(3))) void*)&pk_s[buf][w * 128 + q * 64], \
                16, 0, 0);                                                      \
        }                                                                       \
        if (lane < 32) {                                                        \
            const float* ge = EPI + ((size_t)(ntv) * 128 + w * 32 + lane) * 4;  \
            __builtin_amdgcn_global_load_lds(                                   \
                (const __attribute__((address_space(1))) void*)ge,              \
                (__attribute__((address_space(3))) void*)&ep_s[buf][w * 32],    \
                16, 0, 0);                                                      \
        }                                                                       \
    } while (0)

// exps + projection for one layer (4 rows); o2 packed pairwise for pk_fma
#define EXPPROJ(accv, ev)                                          \
    do {                                                           \
        floatx2 exy_ = { (ev).x, (ev).y };                         \
        floatx2 ezz_ = { (ev).z, (ev).z };                         \
        float rv0_ = __builtin_amdgcn_exp2f((accv)[0]);            \
        float rv1_ = __builtin_amdgcn_exp2f((accv)[1]);            \
        float rv2_ = __builtin_amdgcn_exp2f((accv)[2]);            \
        float rv3_ = __builtin_amdgcn_exp2f((accv)[3]);            \
        o01[0] += (floatx2){rv0_, rv0_} * exy_;                    \
        o01[1] += (floatx2){rv1_, rv1_} * exy_;                    \
        o01[2] += (floatx2){rv2_, rv2_} * exy_;                    \
        o01[3] += (floatx2){rv3_, rv3_} * exy_;                    \
        oz[0]  += (floatx2){rv0_, rv1_} * ezz_;                    \
        oz[1]  += (floatx2){rv2_, rv3_} * ezz_;                    \
    } while (0)

    STAGE(0, 0);   // issue first LDS fill; hides under the af-build below

    // A-fragments for all 8 layers (32 VGPRs), built once, STATIC index only
    short8 af[LN];
#pragma unroll
    for (int j = 0; j < LN; ++j) {
        float4 xa = *(const float4*)(xrow + j * FD);
        CVT(af[j], xa);
    }

    floatx2 o01[4];   // per-row {sum*W'0, sum*W'1}
    floatx2 oz[2];    // rows packed pairwise for W'2
#pragma unroll
    for (int r = 0; r < 4; ++r) o01[r] = (floatx2){0.f, 0.f};
    oz[0] = (floatx2){0.f, 0.f}; oz[1] = (floatx2){0.f, 0.f};

    __syncthreads();

#pragma unroll 1
    for (int nt = 0; nt < 16; ++nt) {
        int cur = nt & 1;
        if (nt < 15) STAGE(cur ^ 1, nt + 1);

        floatx4 acc = (floatx4){0.f, 0.f, 0.f, 0.f};
        floatx4 accp;   // one-j-lag snapshot (written before first read)

#pragma unroll
        for (int j = 0; j < LN; ++j) {
            short8 bf = pk_s[cur][j * 64 + lane];
            acc = __builtin_amdgcn_mfma_f32_16x16x32_bf16(af[j], bf, acc, 0, 0, 0);
            if (j > 0) {                   // finish layer j-1 while MFMA j flies
                float4 e = ep_s[cur][(j - 1) * 16 + m];
                EXPPROJ(accp, e);
            }
            accp = acc;                    // snapshot after MFMA j completes
        }
        {   // tail: layer 7
            float4 e = ep_s[cur][7 * 16 + m];
            EXPPROJ(accp, e);
        }
        __syncthreads();
    }
#undef STAGE
#undef EXPPROJ

    // reduce over the 16 n-lanes (xor 1,2,4,8 stays within kq group)
    float oacc[12];
#pragma unroll
    for (int r = 0; r < 4; ++r) {
        oacc[r * 3 + 0] = o01[r].x;
        oacc[r * 3 + 1] = o01[r].y;
        oacc[r * 3 + 2] = (r & 1) ? oz[r >> 1].y : oz[r >> 1].x;
    }
#pragma unroll
    for (int i = 0; i < 12; ++i) {
        oacc[i] += __shfl_xor(oacc[i], 1);
        oacc[i] += __shfl_xor(oacc[i], 2);
        oacc[i] += __shfl_xor(oacc[i], 4);
        oacc[i] += __shfl_xor(oacc[i], 8);
    }

    if (tvalid && m < OUTD) {
        float bv = bias[m];
#pragma unroll
        for (int r = 0; r < 4; ++r) {
            int row = b0 + kq * 4 + r;     // D-row = (lane>>4)*4 + reg
            if (row < B) out[(size_t)row * OUTD + m] = oacc[r * 3 + m] + bv;
        }
    }
}

extern "C" void kernel_launch(void* const* d_in, const int* in_sizes, int n_in,
                              void* d_out, int out_size, void* d_ws, size_t ws_size,
                              hipStream_t stream) {
    // inputs: 0=x (UNUSED by reference), 1=feats, 2=centers, 3=betas, 4=W, 5=b
    const float* feats   = (const float*)d_in[1];
    const float* centers = (const float*)d_in[2];
    const float* betas   = (const float*)d_in[3];
    const float* W       = (const float*)d_in[4];
    const float* bias    = (const float*)d_in[5];
    float* out = (float*)d_out;
    int B = in_sizes[1] / (LN * FD);

    short* PKB = (short*)d_ws;                       // 65536 shorts = 128 KB
    float* EPI = (float*)((char*)d_ws + 65536 * 2);  // 8192 floats = 32 KB

    prep<<<40, 256, 0, stream>>>(centers, betas, W, PKB, EPI);

    int tiles  = (B + 15) / 16;
    int blocks = (tiles + 3) / 4;
    rbf_mfma<<<blocks, 256, 0, stream>>>(feats, PKB, EPI, bias, out, B);
}